// Round 7
// baseline (1391.604 us; speedup 1.0000x reference)
//
#include <hip/hip_runtime.h>
#include <math.h>

#define TOKS (128*199)   // 25472
#define DM 128
#define DI 256
#define DS 16
#define DR 8
#define NBLK 4
#define LSEQ 199
#define BATCH 128

typedef __attribute__((ext_vector_type(8))) short bf16x8;
typedef __attribute__((ext_vector_type(4))) float f32x4;

__device__ __forceinline__ float gelu_f(float x) {
  return 0.5f * x * (1.0f + erff(x * 0.70710678118654752440f));
}
__device__ __forceinline__ float silu_fast(float x) {
  float e = __expf(-x);
  return x * __builtin_amdgcn_rcpf(1.0f + e);
}
__device__ __forceinline__ unsigned short f2bf(float f) {   // round-to-nearest-even
  unsigned u = __float_as_uint(f);
  u += 0x7fffu + ((u >> 16) & 1u);
  return (unsigned short)(u >> 16);
}
__device__ __forceinline__ float bf2f(unsigned short h) {
  return __uint_as_float(((unsigned)h) << 16);
}

// ---------------- Weight pre-convert: f32 -> (hi, lo) bf16 ----------------
__global__ __launch_bounds__(256) void cvtw_kernel(const float* __restrict__ src,
                                                   unsigned short* __restrict__ dh,
                                                   unsigned short* __restrict__ dl, int n) {
  int i = blockIdx.x*256 + threadIdx.x;
  if (i < n) {
    float v = src[i];
    unsigned short h = f2bf(v);
    dh[i] = h;
    dl[i] = f2bf(v - bf2f(h));
  }
}
// xproj_w [NBLK][40][256] -> padded [NBLK][64][256]
__global__ __launch_bounds__(256) void cvtw_pad_kernel(const float* __restrict__ src,
                                                       unsigned short* __restrict__ dh,
                                                       unsigned short* __restrict__ dl) {
  int i = blockIdx.x*256 + threadIdx.x;      // over 4*64*256
  int blk = i >> 14, rem = i & 16383;
  int r = rem >> 8, c = rem & 255;
  float v = (r < 40) ? src[(size_t)blk*40*256 + r*256 + c] : 0.f;
  unsigned short h = f2bf(v);
  dh[i] = h;
  dl[i] = f2bf(v - bf2f(h));
}

// ---------------- Stem: conv1d stride 5, kernel 10, 12 leads -> 128 ch ----------------
__global__ __launch_bounds__(256) void pe_conv_kernel(
    const float* __restrict__ x, const float* __restrict__ pw,
    const float* __restrict__ pb, float* __restrict__ convo) {
  int b = blockIdx.x, tc = blockIdx.y;
  int t0 = tc * 25;
  int nt = (LSEQ - t0 < 25) ? (LSEQ - t0) : 25;
  __shared__ float sx[12][136];
  int tid = threadIdx.x;
  for (int i = tid; i < 12*136; i += 256) {
    int l = i / 136, k = i - l*136;
    int idx = t0*5 + k;
    sx[l][k] = (idx < 1000) ? x[(size_t)b*12000 + l*1000 + idx] : 0.f;
  }
  __syncthreads();
  for (int o = tid; o < DM*nt; o += 256) {
    int m = o / nt, tt = o - m*nt;
    const float* wr = pw + m*120;
    float acc = pb[m];
#pragma unroll
    for (int l = 0; l < 12; ++l) {
#pragma unroll
      for (int k = 0; k < 10; ++k)
        acc += sx[l][tt*5 + k] * wr[l*10 + k];
    }
    convo[((size_t)b*DM + m)*LSEQ + t0 + tt] = acc;
  }
}

// ---------------- GroupNorm(8 groups) + GELU + transpose + pos add ----------------
__global__ void gn_kernel(const float* __restrict__ conv, const float* __restrict__ gg,
                          const float* __restrict__ gb, const float* __restrict__ pos,
                          float* __restrict__ h) {
  int b = blockIdx.x >> 3, grp = blockIdx.x & 7;
  const float* cb = conv + ((size_t)b*DM + grp*16)*LSEQ;
  int tid = threadIdx.x;
  float s = 0.f, s2 = 0.f;
  for (int i = tid; i < 16*LSEQ; i += 256) { float v = cb[i]; s += v; s2 += v*v; }
#pragma unroll
  for (int m = 1; m < 64; m <<= 1) { s += __shfl_xor(s, m); s2 += __shfl_xor(s2, m); }
  __shared__ float red[8];
  int lane = tid & 63, wid = tid >> 6;
  if (lane == 0) { red[wid] = s; red[4+wid] = s2; }
  __syncthreads();
  float S  = red[0]+red[1]+red[2]+red[3];
  float S2 = red[4]+red[5]+red[6]+red[7];
  const float inv = 1.0f/(16.0f*LSEQ);
  float mean = S*inv;
  float var  = S2*inv - mean*mean;
  float rstd = rsqrtf(var + 1e-5f);
  for (int i = tid; i < 16*LSEQ; i += 256) {
    int mloc = i / LSEQ; int t = i - mloc*LSEQ;
    int m = grp*16 + mloc;
    float v = (cb[i] - mean)*rstd*gg[m] + gb[m];
    v = gelu_f(v);
    h[((size_t)b*LSEQ + t)*DM + m] = v + pos[t*DM + m];
  }
}

// ---------------- LayerNorm over DM=128 -> bf16 hi/lo pair ----------------
__global__ void ln_kernel(const float* __restrict__ x, const float* __restrict__ g,
                          const float* __restrict__ bb,
                          unsigned short* __restrict__ oh, unsigned short* __restrict__ ol) {
  int tok = blockIdx.x*4 + (threadIdx.x >> 6);
  int lane = threadIdx.x & 63;
  const float* xr = x + (size_t)tok*DM;
  float v0 = xr[lane], v1 = xr[lane+64];
  float s = v0+v1, s2 = v0*v0+v1*v1;
#pragma unroll
  for (int m=1;m<64;m<<=1){ s += __shfl_xor(s,m); s2 += __shfl_xor(s2,m); }
  float mean = s*(1.f/DM);
  float var  = s2*(1.f/DM) - mean*mean;
  float rs = rsqrtf(var+1e-5f);
  float y0 = (v0-mean)*rs*g[lane]+bb[lane];
  float y1 = (v1-mean)*rs*g[lane+64]+bb[lane+64];
  size_t o0 = (size_t)tok*DM + lane;
  unsigned short h0 = f2bf(y0), h1 = f2bf(y1);
  oh[o0]    = h0; ol[o0]    = f2bf(y0 - bf2f(h0));
  oh[o0+64] = h1; ol[o0+64] = f2bf(y1 - bf2f(h1));
}

// ---------------- Pure-bf16 MFMA GEMM: C[M,N] = A[M,K] @ W[N,K]^T (+bias/act/resid) ----
// A,W given as hi/lo bf16 pairs. acc = ah*wh + al*wh + ah*wl.
// MODE 0: C f32    MODE 1: C f32 += (resid)   MODE 2: gelu -> bf16 pair
// MODE 3: split write: cols<256 -> Cf (stride 256), cols>=256 -> Cf2 (stride 256)
template<int MODE, int BIAS>
__global__ __launch_bounds__(256) void gemm_bf(
    const unsigned short* __restrict__ Ah, const unsigned short* __restrict__ Al,
    const unsigned short* __restrict__ Wh, const unsigned short* __restrict__ Wl,
    const float* __restrict__ bias,
    float* __restrict__ Cf, unsigned short* __restrict__ Ch, unsigned short* __restrict__ Cl,
    float* __restrict__ Cf2, int N, int K) {
  __shared__ unsigned short sAh[64*32], sAl[64*32], sWh[64*32], sWl[64*32];
  int tid = threadIdx.x;
  int w = tid >> 6, l = tid & 63;
  int fr = l & 15, fq = l >> 4;
  int srow = tid >> 2, sseg = tid & 3;
  const unsigned short* pAh = Ah + (size_t)(blockIdx.x*64 + srow)*K + sseg*8;
  const unsigned short* pAl = Al + (size_t)(blockIdx.x*64 + srow)*K + sseg*8;
  const unsigned short* pWh = Wh + (size_t)(blockIdx.y*64 + srow)*K + sseg*8;
  const unsigned short* pWl = Wl + (size_t)(blockIdx.y*64 + srow)*K + sseg*8;
  f32x4 acc[4];
#pragma unroll
  for (int ns=0;ns<4;++ns) acc[ns] = (f32x4){0.f,0.f,0.f,0.f};
  uint4 vah = *(const uint4*)pAh;
  uint4 val_ = *(const uint4*)pAl;
  uint4 vwh = *(const uint4*)pWh;
  uint4 vwl = *(const uint4*)pWl;
  int sidx = srow*32 + sseg*8;
  for (int k0 = 0; k0 < K; k0 += 32) {
    __syncthreads();                       // previous iter's LDS reads complete
    *(uint4*)&sAh[sidx] = vah;
    *(uint4*)&sAl[sidx] = val_;
    *(uint4*)&sWh[sidx] = vwh;
    *(uint4*)&sWl[sidx] = vwl;
    __syncthreads();
    if (k0 + 32 < K) {                     // prefetch next K-step (overlaps MFMA)
      vah = *(const uint4*)(pAh + k0 + 32);
      val_ = *(const uint4*)(pAl + k0 + 32);
      vwh = *(const uint4*)(pWh + k0 + 32);
      vwl = *(const uint4*)(pWl + k0 + 32);
    }
    bf16x8 ah = *(const bf16x8*)&sAh[(w*16+fr)*32 + fq*8];
    bf16x8 al = *(const bf16x8*)&sAl[(w*16+fr)*32 + fq*8];
#pragma unroll
    for (int ns=0;ns<4;++ns) {
      bf16x8 wh = *(const bf16x8*)&sWh[(ns*16+fr)*32 + fq*8];
      bf16x8 wl = *(const bf16x8*)&sWl[(ns*16+fr)*32 + fq*8];
      acc[ns] = __builtin_amdgcn_mfma_f32_16x16x32_bf16(ah, wh, acc[ns], 0, 0, 0);
      acc[ns] = __builtin_amdgcn_mfma_f32_16x16x32_bf16(al, wh, acc[ns], 0, 0, 0);
      acc[ns] = __builtin_amdgcn_mfma_f32_16x16x32_bf16(ah, wl, acc[ns], 0, 0, 0);
    }
  }
  int row0 = blockIdx.x*64 + w*16 + fq*4;
#pragma unroll
  for (int ns=0;ns<4;++ns) {
    int col = blockIdx.y*64 + ns*16 + fr;
    float bv = BIAS ? bias[col] : 0.f;
#pragma unroll
    for (int v=0;v<4;++v) {
      float val = acc[ns][v] + bv;
      size_t row = (size_t)(row0 + v);
      if (MODE == 0) {
        Cf[row*N + col] = val;
      } else if (MODE == 1) {
        Cf[row*N + col] += val;
      } else if (MODE == 2) {
        val = gelu_f(val);
        unsigned short hh = f2bf(val);
        Ch[row*N + col] = hh;
        Cl[row*N + col] = f2bf(val - bf2f(hh));
      } else {
        if (col < 256) Cf[row*256 + col] = val;
        else           Cf2[row*256 + (col-256)] = val;
      }
    }
  }
}

// ---------------- Depthwise causal conv (k=4) + bias + SiLU -> f32 + bf16 pair --------
__global__ void dwconv_kernel(const float* __restrict__ X, const float* __restrict__ w,
                              const float* __restrict__ bias, float* __restrict__ uss,
                              unsigned short* __restrict__ ussh, unsigned short* __restrict__ ussl) {
  int tok = blockIdx.x;
  int d = threadIdx.x;
  int t = tok % LSEQ;
  float4 wv = *(const float4*)(w + d*4);
  float acc = bias[d];
  const float* xp = X + (size_t)tok*DI + d;
  if (t >= 3) acc += xp[-3*DI]*wv.x;
  if (t >= 2) acc += xp[-2*DI]*wv.y;
  if (t >= 1) acc += xp[-1*DI]*wv.z;
  acc += xp[0]*wv.w;
  float sv = silu_fast(acc);
  size_t o = (size_t)tok*DI + d;
  uss[o] = sv;
  unsigned short hh = f2bf(sv);
  ussh[o] = hh;
  ussl[o] = f2bf(sv - bf2f(hh));
}

// ---------------- dtproj (8->256) + softplus; 8 tokens per block; dbl stride 64 -------
__global__ __launch_bounds__(256) void dtproj_kernel(
    const float* __restrict__ dbl, const float* __restrict__ dtw,
    const float* __restrict__ dtb, float* __restrict__ dlt) {
  int tok0 = blockIdx.x * 8;
  int d = threadIdx.x;
  __shared__ float sdt[8][DR];
  if (d < 64) sdt[d >> 3][d & 7] = dbl[(size_t)(tok0 + (d >> 3))*64 + (d & 7)];
  float wreg[DR];
#pragma unroll
  for (int rr = 0; rr < DR; ++rr) wreg[rr] = dtw[d*DR + rr];
  float b0 = dtb[d];
  __syncthreads();
#pragma unroll
  for (int tt = 0; tt < 8; ++tt) {
    float acc = b0;
#pragma unroll
    for (int rr = 0; rr < DR; ++rr) acc += sdt[tt][rr]*wreg[rr];
    acc = (acc > 20.f) ? acc : log1pf(__expf(acc));
    dlt[(size_t)(tok0 + tt)*DI + d] = acc;
  }
}

// ---------------- Selective scan, state-parallel; y -> bf16 hi/lo pair ----------------
__global__ __launch_bounds__(256) void scan_kernel(
    const float* __restrict__ uss, const float* __restrict__ dlt,
    const float* __restrict__ dbl,
    const float* __restrict__ A_log, const float* __restrict__ Dp,
    const float* __restrict__ Z,
    unsigned short* __restrict__ yh, unsigned short* __restrict__ yl) {
  int bg = blockIdx.x;
  int b = bg >> 4, dg = bg & 15;
  int tid = threadIdx.x;
  int s = tid & 15, dloc = tid >> 4;
  int d = dg*16 + dloc;
  float As = -__expf(A_log[d*DS + s]);
  float Dd = Dp[d];
  float h = 0.f;
  size_t tokbase = (size_t)b*LSEQ;
  const float* pdt = dlt + tokbase*DI + d;
  const float* pu  = uss + tokbase*DI + d;
  const float* pz  = Z   + tokbase*DI + d;
  const float* pB  = dbl + tokbase*64 + 8  + s;
  const float* pC  = dbl + tokbase*64 + 24 + s;
  size_t ooff = tokbase*DI + d;
  float dt_c = *pdt, u_c = *pu, z_c = *pz, B_c = *pB, C_c = *pC;
  for (int t = 0; t < LSEQ; ++t) {
    float dt = dt_c, u = u_c, z = z_c, Bv = B_c, Cv = C_c;
    if (t + 1 < LSEQ) {     // prefetch next step while computing this one
      pdt += DI; pu += DI; pz += DI; pB += 64; pC += 64;
      dt_c = *pdt; u_c = *pu; z_c = *pz; B_c = *pB; C_c = *pC;
    }
    float dA = __expf(dt*As);
    h = fmaf(dA, h, dt*u*Bv);
    float p = h*Cv;
    p += __shfl_xor(p, 1);
    p += __shfl_xor(p, 2);
    p += __shfl_xor(p, 4);
    p += __shfl_xor(p, 8);
    if (s == 0) {
      float yv = fmaf(u, Dd, p) * silu_fast(z);
      unsigned short hh = f2bf(yv);
      yh[ooff] = hh;
      yl[ooff] = f2bf(yv - bf2f(hh));
    }
    ooff += DI;
  }
}

// ---------------- Final: LN + mean over t + head GEMM + GELU ----------------
__global__ void final_kernel(const float* __restrict__ h, const float* __restrict__ g,
                             const float* __restrict__ bta, const float* __restrict__ hw,
                             const float* __restrict__ hb, float* __restrict__ out) {
  int b = blockIdx.x;
  int tid = threadIdx.x, lane = tid & 63, wid = tid >> 6;
  float s0 = 0.f, s1 = 0.f;
  for (int t = wid; t < LSEQ; t += 4) {
    const float* hr = h + ((size_t)b*LSEQ + t)*DM;
    float v0 = hr[lane], v1 = hr[lane+64];
    float ss = v0+v1, ss2 = v0*v0+v1*v1;
#pragma unroll
    for (int m=1;m<64;m<<=1){ ss += __shfl_xor(ss,m); ss2 += __shfl_xor(ss2,m); }
    float mean = ss*(1.f/DM);
    float var  = ss2*(1.f/DM)-mean*mean;
    float rs = rsqrtf(var+1e-5f);
    s0 += (v0-mean)*rs*g[lane]+bta[lane];
    s1 += (v1-mean)*rs*g[lane+64]+bta[lane+64];
  }
  __shared__ float sm[4][128];
  sm[wid][lane] = s0; sm[wid][lane+64] = s1;
  __syncthreads();
  __shared__ float mv[128];
  if (tid < 128) mv[tid] = (sm[0][tid]+sm[1][tid]+sm[2][tid]+sm[3][tid]) * (1.f/199.f);
  __syncthreads();
  int j = tid;  // 256 outputs
  const float* wr = hw + (size_t)j*DM;
  float acc = hb[j];
#pragma unroll 4
  for (int k=0;k<DM;k++) acc += mv[k]*wr[k];
  out[(size_t)b*256 + j] = gelu_f(acc);
}

extern "C" void kernel_launch(void* const* d_in, const int* in_sizes, int n_in,
                              void* d_out, int out_size, void* d_ws, size_t ws_size,
                              hipStream_t stream) {
  const float* x       = (const float*)d_in[0];
  const float* pe_w    = (const float*)d_in[1];
  const float* pe_b    = (const float*)d_in[2];
  const float* gn_g    = (const float*)d_in[3];
  const float* gn_b    = (const float*)d_in[4];
  const float* pos     = (const float*)d_in[5];
  const float* ln1_g   = (const float*)d_in[6];
  const float* ln1_b   = (const float*)d_in[7];
  const float* in_w    = (const float*)d_in[8];
  const float* conv_w  = (const float*)d_in[9];
  const float* conv_b  = (const float*)d_in[10];
  const float* xproj_w = (const float*)d_in[11];
  const float* dtproj_w= (const float*)d_in[12];
  const float* dtproj_b= (const float*)d_in[13];
  const float* A_log   = (const float*)d_in[14];
  const float* Dp      = (const float*)d_in[15];
  const float* outw    = (const float*)d_in[16];
  const float* ln2_g   = (const float*)d_in[17];
  const float* ln2_b   = (const float*)d_in[18];
  const float* ffn_w1  = (const float*)d_in[19];
  const float* ffn_b1  = (const float*)d_in[20];
  const float* ffn_w2  = (const float*)d_in[21];
  const float* ffn_b2  = (const float*)d_in[22];
  const float* lnf_g   = (const float*)d_in[23];
  const float* lnf_b   = (const float*)d_in[24];
  const float* head_w  = (const float*)d_in[25];
  const float* head_b  = (const float*)d_in[26];
  float* out = (float*)d_out;

  // ---- workspace layout ----
  float* ws  = (float*)d_ws;
  float* h    = ws;                           // TOKS*128 f32
  float* X    = h   + (size_t)TOKS*DM;        // TOKS*256 f32 (stem conv buf / in_proj x-half)
  float* Z    = X   + (size_t)TOKS*DI;        // TOKS*256 f32 (in_proj z-half)
  float* uss  = Z   + (size_t)TOKS*DI;        // TOKS*256 f32
  float* dlt  = uss + (size_t)TOKS*DI;        // TOKS*256 f32 (delta)
  float* dbl  = dlt + (size_t)TOKS*DI;        // TOKS*64  f32 (xproj out, padded)
  unsigned short* uh   = (unsigned short*)(dbl + (size_t)TOKS*64);  // TOKS*128
  unsigned short* ul   = uh   + (size_t)TOKS*DM;
  unsigned short* ussh = ul   + (size_t)TOKS*DM;                    // TOKS*256
  unsigned short* ussl = ussh + (size_t)TOKS*DI;
  unsigned short* wb   = ussl + (size_t)TOKS*DI;   // weight pairs
  unsigned short* inwh = wb;                  // 4*512*128
  unsigned short* inwl = inwh + 262144;
  unsigned short* xpwh = inwl + 262144;       // 4*64*256 (padded)
  unsigned short* xpwl = xpwh + 65536;
  unsigned short* outwh= xpwl + 65536;        // 4*128*256
  unsigned short* outwl= outwh + 131072;
  unsigned short* w1h  = outwl + 131072;      // 4*512*128
  unsigned short* w1l  = w1h + 262144;
  unsigned short* w2h  = w1l + 262144;        // 4*128*512
  unsigned short* w2l  = w2h + 262144;
  // aliases over dead f32 regions:
  unsigned short* yh   = (unsigned short*)X;   // TOKS*256 (X dead after dwconv)
  unsigned short* yl   = yh + (size_t)TOKS*DI;
  unsigned short* f1h  = (unsigned short*)uss; // TOKS*512 (uss+dlt dead after scan)
  unsigned short* f1l  = f1h + (size_t)TOKS*512;

  // ---- weight pre-convert (runs every launch; deterministic) ----
  cvtw_kernel<<<1024, 256, 0, stream>>>(in_w,   inwh, inwl, 262144);
  cvtw_pad_kernel<<<256, 256, 0, stream>>>(xproj_w, xpwh, xpwl);
  cvtw_kernel<<<512, 256, 0, stream>>>(outw,   outwh, outwl, 131072);
  cvtw_kernel<<<1024, 256, 0, stream>>>(ffn_w1, w1h, w1l, 262144);
  cvtw_kernel<<<1024, 256, 0, stream>>>(ffn_w2, w2h, w2l, 262144);

  pe_conv_kernel<<<dim3(BATCH, 8), 256, 0, stream>>>(x, pe_w, pe_b, X);
  gn_kernel<<<BATCH*8, 256, 0, stream>>>(X, gn_g, gn_b, pos, h);

  for (int i = 0; i < NBLK; ++i) {
    ln_kernel<<<TOKS/4, 256, 0, stream>>>(h, ln1_g + i*DM, ln1_b + i*DM, uh, ul);
    gemm_bf<3,0><<<dim3(TOKS/64, 8), 256, 0, stream>>>(           // in_proj -> X | Z
        uh, ul, inwh + (size_t)i*65536, inwl + (size_t)i*65536,
        nullptr, X, nullptr, nullptr, Z, 512, DM);
    dwconv_kernel<<<TOKS, 256, 0, stream>>>(X, conv_w + i*DI*4, conv_b + i*DI,
                                            uss, ussh, ussl);
    gemm_bf<0,0><<<dim3(TOKS/64, 1), 256, 0, stream>>>(           // xproj -> dbl[.,64]
        ussh, ussl, xpwh + (size_t)i*16384, xpwl + (size_t)i*16384,
        nullptr, dbl, nullptr, nullptr, nullptr, 64, DI);
    dtproj_kernel<<<TOKS/8, 256, 0, stream>>>(
        dbl, dtproj_w + (size_t)i*DI*DR, dtproj_b + i*DI, dlt);
    scan_kernel<<<BATCH*16, 256, 0, stream>>>(
        uss, dlt, dbl, A_log + (size_t)i*DI*DS, Dp + i*DI, Z, yh, yl);
    gemm_bf<1,0><<<dim3(TOKS/64, 2), 256, 0, stream>>>(           // outw -> h (+resid)
        yh, yl, outwh + (size_t)i*32768, outwl + (size_t)i*32768,
        nullptr, h, nullptr, nullptr, nullptr, DM, DI);
    ln_kernel<<<TOKS/4, 256, 0, stream>>>(h, ln2_g + i*DM, ln2_b + i*DM, uh, ul);
    gemm_bf<2,1><<<dim3(TOKS/64, 8), 256, 0, stream>>>(           // ffn1 -> gelu bf16 pair
        uh, ul, w1h + (size_t)i*65536, w1l + (size_t)i*65536,
        ffn_b1 + i*512, nullptr, f1h, f1l, nullptr, 512, DM);
    gemm_bf<1,1><<<dim3(TOKS/64, 2), 256, 0, stream>>>(           // ffn2 -> h (+resid)
        f1h, f1l, w2h + (size_t)i*65536, w2l + (size_t)i*65536,
        ffn_b2 + i*DM, h, nullptr, nullptr, nullptr, DM, 512);
  }

  final_kernel<<<BATCH, 256, 0, stream>>>(h, lnf_g, lnf_b, head_w, head_b, out);
}